// Round 10
// baseline (298.573 us; speedup 1.0000x reference)
//
#include <hip/hip_runtime.h>
#include <stdint.h>

// BilinearScorer: out[n,r] = sum_{h,k} pred[n,h] U[h,r,k] args[n,k] + bias1[r,:].args[n,:] + bias2[r]
// n=4096, h=k=512, R=64.  137.4 GFLOP fp32-equivalent.
// R15 = R14 (256^2 8-wave 4-phase counted-vmcnt, verified) + fast epilogue.
// R14 post-mortem: main 173us = R11's 175 despite the deep pipeline; MfmaUtil stuck
// at 34.7%. Accounting: block = 45k cyc; K-loop = 12-24k; the rest is the epilogue
// (128 scalar global gathers + 160 shfl / thread) fully EXPOSED at 1 block/CU (R11
// hid it under other blocks' K-loops). Fix the epilogue on the better K-loop:
// (1) args gathers -> per-wave private LDS strips (32x64 f32, stride 66 = <=2-way
//     banks), coalesced float4 staging, bit-identical math order;
// (2) phase 4 reuses bL/bH regs from phase 1 (buffer unmodified between) — kills
//     4 redundant ds_reads/wave/tile (-14% K-loop LDS traffic).
// vmcnt ledger unchanged from R14 (verified). No fences/atomics (R10 lesson).

#define HID   512
#define ROLES 64
#define NTOK  4096
#define BM    256
#define BN    256
#define BK    64

typedef __attribute__((ext_vector_type(8))) _Float16 f16x8;  // MFMA A/B operand: 4 VGPRs
typedef __attribute__((ext_vector_type(4))) _Float16 f16x4;
typedef __attribute__((ext_vector_type(4))) float    f32x4;

__device__ __forceinline__ void async16(const void* g, void* l) {
  // global -> LDS direct copy, 16B/lane. LDS dest is wave-uniform base + lane*16;
  // per-lane SOURCE address is free (implements the store-side swizzle).
  __builtin_amdgcn_global_load_lds(
      (const __attribute__((address_space(1))) uint32_t*)g,
      (__attribute__((address_space(3))) uint32_t*)l, 16, 0, 0);
}

// ---- fused prep: blocks [0,2048) transpose U; [2048,4096) convert pred ----
__global__ __launch_bounds__(256) void prep_fused(
    const float* __restrict__ pred_in, _Float16* __restrict__ predf,
    const float* __restrict__ U, _Float16* __restrict__ ut) {
  __shared__ float tile[128][65];                // pad 65: col-reads 4-way max
  const int bx = blockIdx.x;
  const int t  = threadIdx.x;

  if (bx >= 2048) {                              // ---- cvt_pred path ----
    const int idx = (bx - 2048) * 256 + t;       // 2048 blocks x 256 x float4
    const float4 v = ((const float4*)pred_in)[idx];
    f16x4 o;
    o[0] = (_Float16)v.x; o[1] = (_Float16)v.y;
    o[2] = (_Float16)v.z; o[3] = (_Float16)v.w;
    ((f16x4*)predf)[idx] = o;
    return;
  }

  // ---- cvt_u path: grid-flattened (kb 8, hb 4, r 64) ----
  const int kb = bx & 7, hb = (bx >> 3) & 3, r = bx >> 5;
  const int h0 = hb * 128, k0 = kb * 64;
  const int rr = t >> 4, c4 = (t & 15) * 4;
#pragma unroll
  for (int pass = 0; pass < 8; pass++) {
    const int row = pass * 16 + rr;
    const float4 v = *(const float4*)(U + ((size_t)(h0 + row) * ROLES + r) * HID + k0 + c4);
    tile[row][c4 + 0] = v.x; tile[row][c4 + 1] = v.y;
    tile[row][c4 + 2] = v.z; tile[row][c4 + 3] = v.w;
  }
  __syncthreads();
  const int kr = t >> 4, hc = (t & 15) * 8;
#pragma unroll
  for (int pass = 0; pass < 4; pass++) {
    const int k = pass * 16 + kr;
    alignas(16) _Float16 hbuf[8];
#pragma unroll
    for (int j = 0; j < 8; j++) hbuf[j] = (_Float16)tile[hc + j][k];
    *(uint4*)(ut + ((size_t)r * HID + k0 + k) * HID + h0 + hc) = *(const uint4*)hbuf;
  }
}

// ---- main fused GEMM: 256^2 tile, 8 waves, 4-phase/K-tile, counted vmcnt ---
__global__ __launch_bounds__(512, 2) void bilinear_mfma(
    const _Float16* __restrict__ predf, const _Float16* __restrict__ utf,
    const float* __restrict__ args, const float* __restrict__ bias1,
    float* __restrict__ part) {
  // [buf][ A: 0..16383 | B: 16384..32767 ] f16 ; 2 x 64KB = 128KB
  __shared__ _Float16 lds[2][32768];

  const int nblk = blockIdx.x, mblk = blockIdx.y, r = blockIdx.z;
  const int m0 = mblk * BM, n0 = nblk * BN;
  const int tid  = threadIdx.x;
  const int lane = tid & 63, wid = tid >> 6;
  const int col  = lane & 15, quad = lane >> 4;
  const int wr = wid >> 2, wc = wid & 3;         // 2 M-bands x 4 N-bands
  const int wm = wr * 128, wn = wc * 64;

  // staging: per call 512 lanes cover 64 rows x 8 chunk-slots; 4 calls (c) per
  // operand per K-tile (rows += 64). LDS slot s of row i holds chunk s ^ (i&7).
  const int i_loc = tid >> 3;                    // 0..63
  const int ko    = ((tid & 7) ^ (i_loc & 7)) * 8;
  const size_t offA = (size_t)(m0 + i_loc) * HID + ko;
  const size_t offB = ((size_t)r * HID + n0 + i_loc) * HID + ko;
  const int ldsOff = tid * 8;                    // f16: wave-uniform + lane*16B

  // reader (R11-verified): chunk q at slot q ^ (row&7); row&7 == col&7.
  const int slotL8 = (quad ^ (col & 7)) * 8;     // k in [0,32)
  const int slotH8 = slotL8 ^ 32;                // k in [32,64)
  int rowA[8], rowB[4];
#pragma unroll
  for (int mt = 0; mt < 8; mt++) rowA[mt] = (wm + mt * 16 + col) * BK;
#pragma unroll
  for (int nt = 0; nt < 4; nt++) rowB[nt] = (wn + nt * 16 + col) * BK;

  f32x4 acc[8][4];
#pragma unroll
  for (int a = 0; a < 8; a++)
#pragma unroll
    for (int b = 0; b < 4; b++) acc[a][b] = (f32x4){0.f, 0.f, 0.f, 0.f};

  auto STAGE = [&](int t, int buf) {             // 8 gload_lds per thread
    _Float16* bA = &lds[buf][0];
    _Float16* bB = &lds[buf][16384];
    const size_t kof = (size_t)t * BK;
#pragma unroll
    for (int c = 0; c < 4; c++) {
      async16(predf + offA + (size_t)(c * 64) * HID + kof, bA + c * 4096 + ldsOff);
      async16(utf   + offB + (size_t)(c * 64) * HID + kof, bB + c * 4096 + ldsOff);
    }
  };

  // prologue: tiles 0,1 staged; wait tile0 only (tile1 stays in flight)
  STAGE(0, 0);
  STAGE(1, 1);
  asm volatile("s_waitcnt vmcnt(8)" ::: "memory");
  __builtin_amdgcn_s_barrier();
  __builtin_amdgcn_sched_barrier(0);

  for (int t = 0; t < 8; ++t) {
    const _Float16* bA = &lds[t & 1][0];
    const _Float16* bB = &lds[t & 1][16384];

    f16x8 aL[4], aH[4], bL[2], bH[2], cL[2], cH[2];

    // phase 1: mt 0-3 x nt 0-1 (12 ds_read_b128, 16 MFMA)
#pragma unroll
    for (int mt = 0; mt < 4; mt++) {
      aL[mt] = *(const f16x8*)(bA + rowA[mt] + slotL8);
      aH[mt] = *(const f16x8*)(bA + rowA[mt] + slotH8);
    }
#pragma unroll
    for (int nt = 0; nt < 2; nt++) {
      bL[nt] = *(const f16x8*)(bB + rowB[nt] + slotL8);
      bH[nt] = *(const f16x8*)(bB + rowB[nt] + slotH8);
    }
    __builtin_amdgcn_s_setprio(1);
#pragma unroll
    for (int mt = 0; mt < 4; mt++)
#pragma unroll
      for (int nt = 0; nt < 2; nt++) {
        acc[mt][nt] = __builtin_amdgcn_mfma_f32_16x16x32_f16(aL[mt], bL[nt], acc[mt][nt], 0, 0, 0);
        acc[mt][nt] = __builtin_amdgcn_mfma_f32_16x16x32_f16(aH[mt], bH[nt], acc[mt][nt], 0, 0, 0);
      }
    __builtin_amdgcn_s_setprio(0);
    __builtin_amdgcn_s_barrier();
    __builtin_amdgcn_sched_barrier(0);

    // phase 2: mt 0-3 x nt 2-3 (4 reads, 16 MFMA)
#pragma unroll
    for (int nt = 0; nt < 2; nt++) {
      cL[nt] = *(const f16x8*)(bB + rowB[nt + 2] + slotL8);
      cH[nt] = *(const f16x8*)(bB + rowB[nt + 2] + slotH8);
    }
    __builtin_amdgcn_s_setprio(1);
#pragma unroll
    for (int mt = 0; mt < 4; mt++)
#pragma unroll
      for (int nt = 0; nt < 2; nt++) {
        acc[mt][nt + 2] = __builtin_amdgcn_mfma_f32_16x16x32_f16(aL[mt], cL[nt], acc[mt][nt + 2], 0, 0, 0);
        acc[mt][nt + 2] = __builtin_amdgcn_mfma_f32_16x16x32_f16(aH[mt], cH[nt], acc[mt][nt + 2], 0, 0, 0);
      }
    __builtin_amdgcn_s_setprio(0);
    __builtin_amdgcn_s_barrier();
    __builtin_amdgcn_sched_barrier(0);

    // phase 3: mt 4-7 x nt 2-3 (8 reads, 16 MFMA)
#pragma unroll
    for (int mt = 0; mt < 4; mt++) {
      aL[mt] = *(const f16x8*)(bA + rowA[mt + 4] + slotL8);
      aH[mt] = *(const f16x8*)(bA + rowA[mt + 4] + slotH8);
    }
    __builtin_amdgcn_s_setprio(1);
#pragma unroll
    for (int mt = 0; mt < 4; mt++)
#pragma unroll
      for (int nt = 0; nt < 2; nt++) {
        acc[mt + 4][nt + 2] = __builtin_amdgcn_mfma_f32_16x16x32_f16(aL[mt], cL[nt], acc[mt + 4][nt + 2], 0, 0, 0);
        acc[mt + 4][nt + 2] = __builtin_amdgcn_mfma_f32_16x16x32_f16(aH[mt], cH[nt], acc[mt + 4][nt + 2], 0, 0, 0);
      }
    __builtin_amdgcn_s_setprio(0);
    __builtin_amdgcn_s_barrier();
    __builtin_amdgcn_sched_barrier(0);

    // phase 4: mt 4-7 x nt 0-1 (NO reads — bL/bH preserved from phase 1;
    // buffer unmodified since, so values identical to a re-read)
    __builtin_amdgcn_s_setprio(1);
#pragma unroll
    for (int mt = 0; mt < 4; mt++)
#pragma unroll
      for (int nt = 0; nt < 2; nt++) {
        acc[mt + 4][nt] = __builtin_amdgcn_mfma_f32_16x16x32_f16(aL[mt], bL[nt], acc[mt + 4][nt], 0, 0, 0);
        acc[mt + 4][nt] = __builtin_amdgcn_mfma_f32_16x16x32_f16(aH[mt], bH[nt], acc[mt + 4][nt], 0, 0, 0);
      }
    __builtin_amdgcn_s_setprio(0);
    __builtin_amdgcn_s_barrier();                // all waves done reading buf[t&1]
    __builtin_amdgcn_sched_barrier(0);

    if (t < 6) {
      STAGE(t + 2, t & 1);                       // overwrite just-freed buffer
      asm volatile("s_waitcnt vmcnt(8)" ::: "memory");   // tile t+1 landed
    } else if (t == 6) {
      asm volatile("s_waitcnt vmcnt(0)" ::: "memory");   // drain tile 7 (tail)
    }
    __builtin_amdgcn_s_barrier();                // consensus: next buf ready
    __builtin_amdgcn_sched_barrier(0);
  }

  __syncthreads();                               // K-loop LDS fully retired

  // epilogue: per-wave private args strip in LDS (32 rows x 64 cols f32,
  // row stride 66 -> <=2-way banks). 4 chunks cover the wave's 128 rows.
  // Reads replace 128 scalar global gathers; math order identical to R14.
  float* astrip = (float*)((char*)&lds[0][0] + (size_t)wid * 8448);
  const int l4 = lane >> 4;                      // row-within-group for staging

  float b1v[4];
#pragma unroll
  for (int nt = 0; nt < 4; nt++)
    b1v[nt] = bias1[r * HID + n0 + wn + nt * 16 + col];

  float sval[8][4];
#pragma unroll
  for (int ch = 0; ch < 4; ch++) {
    const float* gsrc = args + (size_t)(m0 + wm + ch * 32) * HID + n0 + wn;
#pragma unroll
    for (int i = 0; i < 8; i++) {                // 32 rows, coalesced float4
      const int row = i * 4 + l4;
      const float4 v = *(const float4*)(gsrc + (size_t)row * HID + col * 4);
      *(float4*)(astrip + row * 66 + col * 4) = v;
    }
#pragma unroll
    for (int mm = 0; mm < 2; mm++) {
      const int mt = ch * 2 + mm;
#pragma unroll
      for (int reg = 0; reg < 4; reg++) {
        const int mloc = mm * 16 + quad * 4 + reg;   // C/D row = quad*4+reg (m89)
        const float* arow = astrip + mloc * 66 + col;
        float s = 0.f;
#pragma unroll
        for (int nt = 0; nt < 4; nt++)
          s += (acc[mt][nt][reg] + b1v[nt]) * arow[nt * 16];
        s += __shfl_xor(s, 1);
        s += __shfl_xor(s, 2);
        s += __shfl_xor(s, 4);
        s += __shfl_xor(s, 8);                   // reduce 16-lane col group
        sval[mt][reg] = s;
      }
    }
  }

  // cross-wave combine: 4 waves per 128-row band; 3 publish, wc==0 combines.
  float* red = (float*)((char*)&lds[0][0] + 120 * 1024);   // 3KB, above strips
  if (wc != 0 && col == 0) {                     // 3 publisher waves per band
#pragma unroll
    for (int mt = 0; mt < 8; mt++)
#pragma unroll
      for (int reg = 0; reg < 4; reg++)
        red[(wc - 1) * 256 + wm + mt * 16 + quad * 4 + reg] = sval[mt][reg];
  }
  __syncthreads();
  if (wc == 0 && col == 0) {                     // combiner waves (wid 0, 4)
    float* pbase = part + (((size_t)nblk * ROLES + r) << 12) + m0;  // part[nblk][r][m]
#pragma unroll
    for (int mt = 0; mt < 8; mt++) {
      const int row = wm + mt * 16 + quad * 4;
      float4 v;
      v.x = sval[mt][0] + red[row + 0] + red[256 + row + 0] + red[512 + row + 0];
      v.y = sval[mt][1] + red[row + 1] + red[256 + row + 1] + red[512 + row + 1];
      v.z = sval[mt][2] + red[row + 2] + red[256 + row + 2] + red[512 + row + 2];
      v.w = sval[mt][3] + red[row + 3] + red[256 + row + 3] + red[512 + row + 3];
      *(float4*)(pbase + row) = v;
    }
  }
}

// ---- reduce: out[m,r] = sum_nb part[nb][r][m] + bias2[r] ------------------
__global__ __launch_bounds__(256) void reduce_k(const float* __restrict__ part,
                                                const float* __restrict__ b2,
                                                float* __restrict__ out) {
  const int idx = blockIdx.x * 256 + threadIdx.x;   // 262144 = NTOK*ROLES
  const int m = idx >> 6, r = idx & (ROLES - 1);
  float v = b2[r];
#pragma unroll
  for (int nb = 0; nb < 2; nb++)
    v += part[(((size_t)nb * ROLES + r) << 12) + m];
  out[idx] = v;                                   // out[m*64+r] == out[idx]
}

// ---- correctness fallback if workspace is too small (slow, pure fp32) -----
__global__ __launch_bounds__(256) void fallback_k(
    const float* __restrict__ pred, const float* __restrict__ args,
    const float* __restrict__ U, const float* __restrict__ b1,
    const float* __restrict__ b2, float* __restrict__ out) {
  const int idx = blockIdx.x * 256 + threadIdx.x;   // 262144
  const int r = idx >> 12;                          // block-uniform role
  const int n = idx & (NTOK - 1);
  const float* arow = args + (size_t)n * HID;
  const float* prow = pred + (size_t)n * HID;
  float acc = 0.f;
  for (int h = 0; h < HID; h++) {
    const float* urow = U + ((size_t)h * ROLES + r) * HID;
    float s = 0.f;
    for (int k = 0; k < HID; k++) s = fmaf(urow[k], arow[k], s);
    acc = fmaf(prow[h], s, acc);
  }
  float sb = 0.f;
  const float* brow = b1 + (size_t)r * HID;
  for (int k = 0; k < HID; k++) sb = fmaf(brow[k], arow[k], sb);
  out[(size_t)n * ROLES + r] = acc + sb + b2[r];
}

extern "C" void kernel_launch(void* const* d_in, const int* in_sizes, int n_in,
                              void* d_out, int out_size, void* d_ws, size_t ws_size,
                              hipStream_t stream) {
  const float* pred = (const float*)d_in[0];
  const float* args = (const float*)d_in[1];
  const float* U    = (const float*)d_in[2];
  const float* b1   = (const float*)d_in[3];
  const float* b2   = (const float*)d_in[4];
  float* out = (float*)d_out;

  const size_t PRED_ELEMS = (size_t)NTOK * HID;         // 2,097,152
  const size_t U_ELEMS    = (size_t)HID * ROLES * HID;  // 16,777,216
  const size_t PART_ELEMS = (size_t)2 * ROLES * NTOK;   // 524,288 f32 (2 MiB)
  const size_t WS_NEEDED  = (PRED_ELEMS + U_ELEMS) * sizeof(_Float16)
                          + PART_ELEMS * sizeof(float); // ~38 MiB

  if (ws_size < WS_NEEDED) {
    hipLaunchKernelGGL(fallback_k, dim3((NTOK * ROLES) / 256), dim3(256), 0, stream,
                       pred, args, U, b1, b2, out);
    return;
  }

  _Float16* predf = (_Float16*)d_ws;
  _Float16* utf   = predf + PRED_ELEMS;
  float*    partb = (float*)(utf + U_ELEMS);

  hipLaunchKernelGGL(prep_fused, dim3(4096), dim3(256), 0, stream,
                     pred, predf, U, utf);
  hipLaunchKernelGGL(bilinear_mfma, dim3(HID / BN, NTOK / BM, ROLES), dim3(512), 0, stream,
                     predf, utf, args, b1, partb);
  hipLaunchKernelGGL(reduce_k, dim3((NTOK * ROLES) / 256), dim3(256), 0, stream,
                     partb, b2, out);
}